// Round 6
// baseline (232.636 us; speedup 1.0000x reference)
//
#include <hip/hip_runtime.h>
#include <hip/hip_bf16.h>

// GCN 2-layer encoder. R20: R16 structure (bucketed binA + binB LDS build,
// proven best) + SORTED slot lists: binB insertion-sorts each node's slots
// ascending by source id before the coalesced flush. All gather blocks are
// co-resident and progress in lockstep, so sorted lists make every wave read
// sources in a narrow moving address band -> ~17x temporal reuse hits L2
// instead of missing to L3. Gathers keep packed f32x2 accumulate.
// out[d] = dinv[d] * sum_{s in N(d) U {d}} dinv[s]*h[s] + b,  h = in @ W1

constexpr int FIN = 128;
constexpr int HID = 128;
constexpr int FOUT = 64;
constexpr int CAP = 48;     // adjacency slots per node
constexpr int NPB = 98;     // nodes per bucket
constexpr int BCAP = 3072;  // pairs per bucket region
constexpr int OVF_MAX = 65536;

typedef __attribute__((ext_vector_type(8))) short s16x8;
typedef __attribute__((ext_vector_type(4))) float f32x4;
typedef __attribute__((ext_vector_type(2))) float f32x2;

static __device__ __forceinline__ float bf2f(__hip_bfloat16 v) { return __bfloat162float(v); }
static __device__ __forceinline__ float lo2f(unsigned u) { union { unsigned i; float f; } c; c.i = u << 16; return c.f; }
static __device__ __forceinline__ float hi2f(unsigned u) { union { unsigned i; float f; } c; c.i = u & 0xffff0000u; return c.f; }
static __device__ __forceinline__ unsigned short f2bfu(float f) {
    __hip_bfloat16 h = __float2bfloat16(f);
    union { __hip_bfloat16 h; unsigned short u; } c; c.h = h; return c.u;
}
static __device__ __forceinline__ unsigned pack2(float a, float b) {
    return (unsigned)f2bfu(a) | ((unsigned)f2bfu(b) << 16);
}
// bf16-pair word -> {lo, hi} as f32x2 (same bit ops as lo2f/hi2f)
static __device__ __forceinline__ f32x2 unpk(unsigned u) {
    union { unsigned i; float f; } a, b;
    a.i = u << 16; b.i = u & 0xffff0000u;
    f32x2 r; r[0] = a.f; r[1] = b.f; return r;
}
static __device__ __forceinline__ void acc_add(f32x2* acc, uint4 v) {
    acc[0] += unpk(v.x); acc[1] += unpk(v.y);
    acc[2] += unpk(v.z); acc[3] += unpk(v.w);
}
static __device__ __forceinline__ void acc_fma(f32x2* acc, uint4 v, float w) {
    f32x2 ws; ws[0] = w; ws[1] = w;
    acc[0] += ws * unpk(v.x); acc[1] += ws * unpk(v.y);
    acc[2] += ws * unpk(v.z); acc[3] += ws * unpk(v.w);
}

struct SW { int s; float w; };

// flags detect + zero gcur/ovf counters. zero_cnt!=0 (fallback path): zero cnt.
__global__ __launch_bounds__(256) void k_detect(const unsigned* __restrict__ xw,
                                                const int* __restrict__ eiw,
                                                int E, int* __restrict__ flags,
                                                int* __restrict__ gcur,
                                                int* __restrict__ cnt, int N, int zero_cnt) {
    if (zero_cnt)
        for (long i = (long)blockIdx.x * 256 + threadIdx.x; i < N; i += (long)gridDim.x * 256)
            cnt[i] = 0;
    if (blockIdx.x != 0) return;
    for (int i = threadIdx.x; i < 514; i += 256) gcur[i] = 0;
    __shared__ int s_bf16like, s_oddnz;
    if (threadIdx.x == 0) { s_bf16like = 0; s_oddnz = 0; }
    __syncthreads();
    int c = 0;
    for (int i = threadIdx.x; i < 4096; i += 256) {
        unsigned ex = ((xw[i] & 0xffffu) >> 7) & 0xffu;
        if (ex >= 117u && ex <= 130u) c++;
    }
    atomicAdd(&s_bf16like, c);
    int nz = 0;
    for (int i = threadIdx.x; i < 2048; i += 256)
        if (eiw[2 * i + 1] != 0) nz++;
    atomicAdd(&s_oddnz, nz);
    __syncthreads();
    if (threadIdx.x == 0) {
        flags[0] = (s_bf16like < 2048) ? 1 : 0;
        flags[1] = (s_oddnz == 0) ? 1 : 0;
    }
}

// Mega kernel: blocks [0,GB) = gemm1 (unscaled, 2 column planes of 64);
//              blocks [GB,GB+AB) = binA edge partition. Dynamic LDS.
__global__ __launch_bounds__(256) void k_mega(const void* __restrict__ Xp,
                                              const void* __restrict__ Wp,
                                              const int* __restrict__ ei, int E, int N,
                                              int nbuk, int GB,
                                              int* __restrict__ gcur,
                                              unsigned* __restrict__ pairs,
                                              int2* __restrict__ ovfA,
                                              int* __restrict__ ovfAcnt,
                                              __hip_bfloat16* __restrict__ G,
                                              const int* __restrict__ flags) {
    extern __shared__ __align__(16) char smem[];
    const int tid = threadIdx.x;
    if ((int)blockIdx.x < GB) {
        // ---------------- GEMM1: g = X @ W1 (unscaled), 2 column planes ----
        short* Wt = (short*)smem;                    // 128x136 bf16 = 34816 B
        const bool f32m = flags[0] != 0;
        for (int i = tid; i < 128 * 128; i += 256) {
            int k = i >> 7, n = i & 127;
            float wv = f32m ? ((const float*)Wp)[(long)k * 128 + n]
                            : bf2f(((const __hip_bfloat16*)Wp)[(long)k * 128 + n]);
            Wt[n * 136 + k] = (short)f2bfu(wv);
        }
        __syncthreads();
        const int w = tid >> 6, lane = tid & 63;
        const int m = lane & 15, quad = lane >> 4;
        const int rowA = blockIdx.x * 64 + w * 16 + m;
        const int rowc = rowA < N ? rowA : N - 1;
        s16x8 afr[4];
#pragma unroll
        for (int kc = 0; kc < 4; ++kc) {
            const int k0 = kc * 32 + quad * 8;
            if (!f32m) {
                afr[kc] = *(const s16x8*)((const __hip_bfloat16*)Xp + (long)rowc * 128 + k0);
            } else {
                const float* p = (const float*)Xp + (long)rowc * 128 + k0;
                s16x8 t;
#pragma unroll
                for (int j = 0; j < 8; ++j) t[j] = (short)f2bfu(p[j]);
                afr[kc] = t;
            }
        }
        const int rbase = blockIdx.x * 64 + w * 16 + quad * 4;
#pragma unroll
        for (int ct = 0; ct < 8; ++ct) {
            f32x4 acc = {0.f, 0.f, 0.f, 0.f};
#pragma unroll
            for (int kc = 0; kc < 4; ++kc) {
                s16x8 bfr = *(const s16x8*)&Wt[(ct * 16 + m) * 136 + kc * 32 + quad * 8];
                acc = __builtin_amdgcn_mfma_f32_16x16x32_bf16(afr[kc], bfr, acc, 0, 0, 0);
            }
            const int plane = ct >> 2;                 // 2 planes of 64 cols
            const int cp = (ct & 3) * 16 + m;
#pragma unroll
            for (int r = 0; r < 4; ++r) {
                int rr = rbase + r;
                if (rr < N)
                    G[(long)plane * N * 64 + (long)rr * 64 + cp] = __float2bfloat16(acc[r]);
            }
        }
    } else {
        // ---------------- binA: edge partition into buckets ----------------
        int* hist = (int*)smem;          // 512 ints
        int* gbase = hist + 512;         // 512 ints
        const long base = (long)(blockIdx.x - GB) * 2048;
        const bool i64 = flags[1] != 0;
        int se[8], de[8];
        for (int b = tid; b < nbuk; b += 256) hist[b] = 0;
        __syncthreads();
#pragma unroll
        for (int j = 0; j < 8; ++j) {
            long i = base + j * 256 + tid;
            int s = 0, d = -1;
            if (i < E) {
                if (i64) { s = ((const int2*)ei)[i].x; d = ((const int2*)(ei + 2 * (long)E))[i].x; }
                else     { s = ei[i]; d = ei[(long)E + i]; }
                if ((unsigned)s >= (unsigned)N || (unsigned)d >= (unsigned)N) d = -1;
            }
            se[j] = s; de[j] = d;
            if (d >= 0) atomicAdd(&hist[d / NPB], 1);
        }
        __syncthreads();
        for (int b = tid; b < nbuk; b += 256) {
            int h = hist[b];
            gbase[b] = h > 0 ? atomicAdd(&gcur[b], h) : 0;
            hist[b] = 0;
        }
        __syncthreads();
#pragma unroll
        for (int j = 0; j < 8; ++j) {
            int d = de[j];
            if (d < 0) continue;
            int b = d / NPB;
            int p = gbase[b] + atomicAdd(&hist[b], 1);
            if (p < BCAP) {
                pairs[(long)b * BCAP + p] = ((unsigned)(d - b * NPB) << 16) | (unsigned)se[j];
            } else {
                int op = atomicAdd(ovfAcnt, 1);
                if (op < OVF_MAX) ovfA[op] = make_int2(d, se[j]);
            }
        }
    }
}

// Phase B: per bucket, build cnt+slots+dinv in LDS (incl. phase-A ovf fold),
// then sort each node's slot list ascending (lockstep band sweep in gathers).
__global__ __launch_bounds__(256) void k_binB(const int* __restrict__ gcur,
                                              const unsigned* __restrict__ pairs,
                                              const int2* __restrict__ ovfA,
                                              const int* __restrict__ ovfAcnt,
                                              int* __restrict__ cnt,
                                              float* __restrict__ dinv,
                                              unsigned short* __restrict__ slots,
                                              int2* __restrict__ ovf2,
                                              int* __restrict__ ovf2cnt, int N) {
    __shared__ int cntL[NPB];
    __shared__ __align__(16) unsigned short slotsL[NPB * CAP];
    const int b = blockIdx.x;
    const int tid = threadIdx.x;
    const int d0 = b * NPB;
    const int nd = min(NPB, N - d0);
    if (nd <= 0) return;
    for (int i = tid; i < NPB; i += 256) cntL[i] = 0;
    __syncthreads();
    const int c = min(gcur[b], BCAP);
    const unsigned* pb = pairs + (long)b * BCAP;
    for (int i = tid; i < c; i += 256) {
        unsigned p = pb[i];
        int ld = p >> 16;
        int pos = atomicAdd(&cntL[ld], 1);
        if (pos < CAP) {
            slotsL[ld * CAP + pos] = (unsigned short)(p & 0xffffu);
        } else {
            int op = atomicAdd(ovf2cnt, 1);
            if (op < OVF_MAX) ovf2[op] = make_int2(d0 + ld, (int)(p & 0xffffu));
        }
    }
    int na = *ovfAcnt; na = na < OVF_MAX ? na : OVF_MAX;
    for (int i = tid; i < na; i += 256) {
        int2 p = ovfA[i];
        int ld = p.x - d0;
        if ((unsigned)ld < (unsigned)nd) {
            int pos = atomicAdd(&cntL[ld], 1);
            if (pos < CAP) {
                slotsL[ld * CAP + pos] = (unsigned short)p.y;
            } else {
                int op = atomicAdd(ovf2cnt, 1);
                if (op < OVF_MAX) ovf2[op] = p;
            }
        }
    }
    __syncthreads();
    // ---- per-node ascending insertion sort of the slot list (<=CAP elems) --
    for (int ld = tid; ld < nd; ld += 256) {
        const int mloc = min(cntL[ld], CAP);
        unsigned short* row = &slotsL[ld * CAP];
        for (int a = 1; a < mloc; ++a) {
            const unsigned short key = row[a];
            int p = a - 1;
            while (p >= 0 && row[p] > key) { row[p + 1] = row[p]; --p; }
            row[p + 1] = key;
        }
    }
    __syncthreads();
    for (int i = tid; i < nd; i += 256) {
        cnt[d0 + i] = cntL[i];
        dinv[d0 + i] = rsqrtf((float)(cntL[i] + 1));
    }
    const uint4* sv = (const uint4*)slotsL;
    uint4* gv = (uint4*)(slots + (long)d0 * CAP);
    const int total8 = (nd * CAP) >> 3;
    for (int i = tid; i < total8; i += 256) gv[i] = sv[i];
}

// Fallback direct build for N > 65536 (int slots). cnt must be pre-zeroed.
__global__ __launch_bounds__(256) void k_build_direct(const int* __restrict__ ei, int E, int N,
                                                      int* __restrict__ cnt,
                                                      int* __restrict__ slots,
                                                      int2* __restrict__ ovf2,
                                                      int* __restrict__ ovf2cnt,
                                                      const int* __restrict__ flags) {
    long i = (long)blockIdx.x * 256 + threadIdx.x;
    if (i >= E) return;
    int s, d;
    if (flags[1]) { s = ((const int2*)ei)[i].x; d = ((const int2*)(ei + 2 * (long)E))[i].x; }
    else          { s = ei[i]; d = ei[(long)E + i]; }
    if ((unsigned)s >= (unsigned)N || (unsigned)d >= (unsigned)N) return;
    int pos = atomicAdd(&cnt[d], 1);
    if (pos < CAP) {
        slots[(long)d * CAP + pos] = s;
    } else {
        int op = atomicAdd(ovf2cnt, 1);
        if (op < OVF_MAX) ovf2[op] = make_int2(d, s);
    }
}

// Scaled MFMA GEMM (runs after binB): G = bf16( rsqrt(cnt+1) * (X @ W) ).
template<int CT, int SPLIT>
__global__ __launch_bounds__(256) void k_gemm(const void* __restrict__ Xp, int x_follows_flag,
                                              const void* __restrict__ Wp,
                                              const int* __restrict__ cnt,
                                              __hip_bfloat16* __restrict__ G,
                                              const int* __restrict__ flags, int N) {
    constexpr int C = CT * 16;
    __shared__ __align__(16) short Wt[C * 136];
    const bool f32m = flags[0] != 0;
    const bool xf32 = (x_follows_flag != 0) && f32m;
    const int tid = threadIdx.x;
    for (int i = tid; i < 128 * C; i += 256) {
        int k = i / C, n = i % C;
        float wv = f32m ? ((const float*)Wp)[(long)k * C + n]
                        : bf2f(((const __hip_bfloat16*)Wp)[(long)k * C + n]);
        Wt[n * 136 + k] = (short)f2bfu(wv);
    }
    __syncthreads();
    const int w = tid >> 6, lane = tid & 63;
    const int m = lane & 15, quad = lane >> 4;
    const int rowA = blockIdx.x * 64 + w * 16 + m;
    const int rowc = rowA < N ? rowA : N - 1;
    s16x8 afr[4];
#pragma unroll
    for (int kc = 0; kc < 4; ++kc) {
        const int k0 = kc * 32 + quad * 8;
        if (!xf32) {
            afr[kc] = *(const s16x8*)((const __hip_bfloat16*)Xp + (long)rowc * 128 + k0);
        } else {
            const float* p = (const float*)Xp + (long)rowc * 128 + k0;
            s16x8 t;
#pragma unroll
            for (int j = 0; j < 8; ++j) t[j] = (short)f2bfu(p[j]);
            afr[kc] = t;
        }
    }
    const int rbase = blockIdx.x * 64 + w * 16 + quad * 4;
    float dv[4];
#pragma unroll
    for (int r = 0; r < 4; ++r) {
        int rr = min(rbase + r, N - 1);
        dv[r] = rsqrtf((float)(cnt[rr] + 1));
    }
#pragma unroll
    for (int ct = 0; ct < CT; ++ct) {
        f32x4 acc = {0.f, 0.f, 0.f, 0.f};
#pragma unroll
        for (int kc = 0; kc < 4; ++kc) {
            s16x8 bfr = *(const s16x8*)&Wt[(ct * 16 + m) * 136 + kc * 32 + quad * 8];
            acc = __builtin_amdgcn_mfma_f32_16x16x32_bf16(afr[kc], bfr, acc, 0, 0, 0);
        }
#pragma unroll
        for (int r = 0; r < 4; ++r) {
            int rr = rbase + r;
            if (rr < N) {
                long off;
                if (SPLIT) {
                    const int plane = ct / (CT / 2);
                    const int cp = (ct % (CT / 2)) * 16 + m;
                    off = (long)plane * N * (C / 2) + (long)rr * (C / 2) + cp;
                } else {
                    off = (long)rr * C + ct * 16 + m;
                }
                G[off] = __float2bfloat16(dv[r] * acc[r]);
            }
        }
    }
}

// Gather, layer 1 (R16 structure): block owns 32 nodes; slots + per-source
// dinv staged to LDS once (stride-49 pad). 2 planes of [N][64] looped
// in-block. g UNscaled; dinv[s] applied per source. Packed f32x2 accumulate.
// Slot lists arrive SORTED ascending -> lockstep address-band sweep.
__global__ __launch_bounds__(256) void k_gather1b(const __hip_bfloat16* __restrict__ G,
                                                  const int* __restrict__ cnt,
                                                  const float* __restrict__ dinv,
                                                  const unsigned short* __restrict__ slots,
                                                  const int2* __restrict__ ovf2,
                                                  const int* __restrict__ ovf2cnt,
                                                  const void* __restrict__ b1,
                                                  __hip_bfloat16* __restrict__ h1,
                                                  const int* __restrict__ flags, int N) {
    __shared__ int cntL[32];
    __shared__ float wsL[32];
    __shared__ __align__(16) SW swL[32 * 49];     // 12544 B, pad 48->49
    const int tid = threadIdx.x;
    const int n0 = blockIdx.x * 32;
    const int nd = min(32, N - n0);
    for (int i = tid; i < nd; i += 256) {
        cntL[i] = cnt[n0 + i];
        wsL[i] = dinv[n0 + i];
    }
    __syncthreads();
    for (int j = tid; j < 32 * CAP; j += 256) {
        const int ni = j / CAP, sl = j - ni * CAP;
        if (ni < nd) {
            const int mm = min(cntL[ni], CAP);
            if (sl < mm) {
                const int s = slots[(long)(n0 + ni) * CAP + sl];
                swL[ni * 49 + sl].s = s;
                swL[ni * 49 + sl].w = dinv[s];
            }
        }
    }
    __syncthreads();
    const int grp = tid >> 3, lane = tid & 7;
    if (grp >= nd) return;                        // all barriers done
    const int node = n0 + grp;
    const int cd = cntL[grp];
    const int m = cd < CAP ? cd : CAP;
    const float wself = wsL[grp];
    const SW* sw = &swL[grp * 49];
    const bool f32m = flags[0] != 0;
    for (int P = 0; P < 2; ++P) {
        const __hip_bfloat16* Gp = G + (long)P * N * 64;
        f32x2 acc2[4] = {};
        float* acc = (float*)acc2;
        acc_fma(acc2, ((const uint4*)(Gp + (long)node * 64))[lane], wself);  // self
        int i = 0;
        for (; i + 7 < m; i += 8) {
            SW a0 = sw[i], a1 = sw[i + 1], a2 = sw[i + 2], a3 = sw[i + 3];
            SW a4 = sw[i + 4], a5 = sw[i + 5], a6 = sw[i + 6], a7 = sw[i + 7];
            uint4 v0 = ((const uint4*)(Gp + (long)a0.s * 64))[lane];
            uint4 v1 = ((const uint4*)(Gp + (long)a1.s * 64))[lane];
            uint4 v2 = ((const uint4*)(Gp + (long)a2.s * 64))[lane];
            uint4 v3 = ((const uint4*)(Gp + (long)a3.s * 64))[lane];
            uint4 v4 = ((const uint4*)(Gp + (long)a4.s * 64))[lane];
            uint4 v5 = ((const uint4*)(Gp + (long)a5.s * 64))[lane];
            uint4 v6 = ((const uint4*)(Gp + (long)a6.s * 64))[lane];
            uint4 v7 = ((const uint4*)(Gp + (long)a7.s * 64))[lane];
            acc_fma(acc2, v0, a0.w); acc_fma(acc2, v1, a1.w);
            acc_fma(acc2, v2, a2.w); acc_fma(acc2, v3, a3.w);
            acc_fma(acc2, v4, a4.w); acc_fma(acc2, v5, a5.w);
            acc_fma(acc2, v6, a6.w); acc_fma(acc2, v7, a7.w);
        }
        for (; i + 3 < m; i += 4) {
            SW a0 = sw[i], a1 = sw[i + 1], a2 = sw[i + 2], a3 = sw[i + 3];
            uint4 v0 = ((const uint4*)(Gp + (long)a0.s * 64))[lane];
            uint4 v1 = ((const uint4*)(Gp + (long)a1.s * 64))[lane];
            uint4 v2 = ((const uint4*)(Gp + (long)a2.s * 64))[lane];
            uint4 v3 = ((const uint4*)(Gp + (long)a3.s * 64))[lane];
            acc_fma(acc2, v0, a0.w); acc_fma(acc2, v1, a1.w);
            acc_fma(acc2, v2, a2.w); acc_fma(acc2, v3, a3.w);
        }
        for (; i < m; ++i) {
            SW a = sw[i];
            acc_fma(acc2, ((const uint4*)(Gp + (long)a.s * 64))[lane], a.w);
        }
        if (cd > CAP) {
            int oc = *ovf2cnt; oc = oc < OVF_MAX ? oc : OVF_MAX;
            for (int j = 0; j < oc; ++j)
                if (ovf2[j].x == node) {
                    int s0 = ovf2[j].y;
                    acc_fma(acc2, ((const uint4*)(Gp + (long)s0 * 64))[lane], dinv[s0]);
                }
        }
        const int c0 = P * 64 + lane * 8;
        float bv[8];
        if (f32m) {
            const float4* bp = (const float4*)((const float*)b1 + c0);
            float4 b0 = bp[0], b1v = bp[1];
            bv[0] = b0.x; bv[1] = b0.y; bv[2] = b0.z; bv[3] = b0.w;
            bv[4] = b1v.x; bv[5] = b1v.y; bv[6] = b1v.z; bv[7] = b1v.w;
        } else {
            uint4 b = *(const uint4*)((const __hip_bfloat16*)b1 + c0);
            bv[0] = lo2f(b.x); bv[1] = hi2f(b.x); bv[2] = lo2f(b.y); bv[3] = hi2f(b.y);
            bv[4] = lo2f(b.z); bv[5] = hi2f(b.z); bv[6] = lo2f(b.w); bv[7] = hi2f(b.w);
        }
        float o[8];
#pragma unroll
        for (int c = 0; c < 8; ++c) {
            float v = wself * acc[c] + bv[c];
            o[c] = v > 0.f ? v : 0.f;
        }
        uint4 pv = { pack2(o[0], o[1]), pack2(o[2], o[3]), pack2(o[4], o[5]), pack2(o[6], o[7]) };
        ((uint4*)(h1 + (long)node * 128 + P * 64))[lane] = pv;
    }
}

// Full-row gather over pre-scaled G (layer 2 and fallback layer 1).
template<int F, int LAYER1, typename ST>
__global__ __launch_bounds__(256) void k_gather(const __hip_bfloat16* __restrict__ G,
                                                const int* __restrict__ cnt,
                                                const ST* __restrict__ slots,
                                                const int2* __restrict__ ovf2,
                                                const int* __restrict__ ovf2cnt,
                                                const void* __restrict__ bias,
                                                void* __restrict__ outp,
                                                const int* __restrict__ flags, int N) {
    constexpr int L = F / 8;
    constexpr int NODES = 256 / L;
    const int tid = threadIdx.x;
    const int grp = tid / L, lane = tid % L;
    const int node = blockIdx.x * NODES + grp;
    if (node >= N) return;
    const int cd = cnt[node];
    const float wself = rsqrtf((float)(cd + 1));
    const int m = cd < CAP ? cd : CAP;
    const ST* sl = slots + (long)node * CAP;
    f32x2 acc2[4] = {};
    float* acc = (float*)acc2;
    acc_add(acc2, ((const uint4*)(G + (long)node * F))[lane]);
    int i = 0;
    for (; i + 7 < m; i += 8) {
        int s0 = sl[i], s1 = sl[i + 1], s2 = sl[i + 2], s3 = sl[i + 3];
        int s4 = sl[i + 4], s5 = sl[i + 5], s6 = sl[i + 6], s7 = sl[i + 7];
        uint4 v0 = ((const uint4*)(G + (long)s0 * F))[lane];
        uint4 v1 = ((const uint4*)(G + (long)s1 * F))[lane];
        uint4 v2 = ((const uint4*)(G + (long)s2 * F))[lane];
        uint4 v3 = ((const uint4*)(G + (long)s3 * F))[lane];
        uint4 v4 = ((const uint4*)(G + (long)s4 * F))[lane];
        uint4 v5 = ((const uint4*)(G + (long)s5 * F))[lane];
        uint4 v6 = ((const uint4*)(G + (long)s6 * F))[lane];
        uint4 v7 = ((const uint4*)(G + (long)s7 * F))[lane];
        acc_add(acc2, v0); acc_add(acc2, v1); acc_add(acc2, v2); acc_add(acc2, v3);
        acc_add(acc2, v4); acc_add(acc2, v5); acc_add(acc2, v6); acc_add(acc2, v7);
    }
    for (; i + 3 < m; i += 4) {
        int s0 = sl[i], s1 = sl[i + 1], s2 = sl[i + 2], s3 = sl[i + 3];
        uint4 v0 = ((const uint4*)(G + (long)s0 * F))[lane];
        uint4 v1 = ((const uint4*)(G + (long)s1 * F))[lane];
        uint4 v2 = ((const uint4*)(G + (long)s2 * F))[lane];
        uint4 v3 = ((const uint4*)(G + (long)s3 * F))[lane];
        acc_add(acc2, v0); acc_add(acc2, v1); acc_add(acc2, v2); acc_add(acc2, v3);
    }
    for (; i < m; ++i)
        acc_add(acc2, ((const uint4*)(G + (long)sl[i] * F))[lane]);
    if (cd > CAP) {
        int oc = *ovf2cnt; oc = oc < OVF_MAX ? oc : OVF_MAX;
        for (int j = 0; j < oc; ++j)
            if (ovf2[j].x == node)
                acc_add(acc2, ((const uint4*)(G + (long)ovf2[j].y * F))[lane]);
    }
    const bool f32m = flags[0] != 0;
    const int c0 = lane * 8;
    float bv[8];
    if (f32m) {
        const float4* bp = (const float4*)((const float*)bias + c0);
        float4 b0 = bp[0], b1 = bp[1];
        bv[0] = b0.x; bv[1] = b0.y; bv[2] = b0.z; bv[3] = b0.w;
        bv[4] = b1.x; bv[5] = b1.y; bv[6] = b1.z; bv[7] = b1.w;
    } else {
        uint4 b = *(const uint4*)((const __hip_bfloat16*)bias + c0);
        bv[0] = lo2f(b.x); bv[1] = hi2f(b.x); bv[2] = lo2f(b.y); bv[3] = hi2f(b.y);
        bv[4] = lo2f(b.z); bv[5] = hi2f(b.z); bv[6] = lo2f(b.w); bv[7] = hi2f(b.w);
    }
    float o[8];
#pragma unroll
    for (int c = 0; c < 8; ++c) {
        float v = wself * acc[c] + bv[c];
        o[c] = (LAYER1 && v < 0.f) ? 0.f : v;
    }
    if (LAYER1 || !f32m) {
        uint4 pv = { pack2(o[0], o[1]), pack2(o[2], o[3]), pack2(o[4], o[5]), pack2(o[6], o[7]) };
        ((uint4*)outp)[(long)node * L + lane] = pv;
    } else {
        float4* op = (float4*)((float*)outp + (long)node * F + c0);
        op[0] = make_float4(o[0], o[1], o[2], o[3]);
        op[1] = make_float4(o[4], o[5], o[6], o[7]);
    }
}

extern "C" void kernel_launch(void* const* d_in, const int* in_sizes, int n_in,
                              void* d_out, int out_size, void* d_ws, size_t ws_size,
                              hipStream_t stream) {
    const void* x  = d_in[0];
    const int*  ei = (const int*)d_in[1];
    const void* W1 = d_in[2];
    const void* b1 = d_in[3];
    const void* W2 = d_in[4];
    const void* b2 = d_in[5];

    const int N = in_sizes[0] / FIN;   // 50000
    const int E = in_sizes[1] / 2;     // 800000
    const int nbuk = (N + NPB - 1) / NPB;   // 511 (<=512 for u16 path)

    // ws layout (bytes), peak ~37.3MB:
    //   flags @0; gcur @4096 (512+2 ints)
    //   cnt @65536 (4N); dinv @266240 (4N)
    //   ovfA @524288; ovf2 @1048576
    //   slots @2097152 (u16 4.8MB / int 9.6MB)
    //   g @11730944 (12.8MB, 2 planes of N*64; g2 overlays)
    //   pairs @24530944 (6.28MB; h1 overlays after binB)
    char* ws = (char*)d_ws;
    int*   flags   = (int*)ws;
    int*   gcur    = (int*)(ws + 4096);
    int*   ovfAcnt = gcur + 512;
    int*   ovf2cnt = gcur + 513;
    int*   cnt     = (int*)(ws + 65536);
    float* dinv    = (float*)(ws + 266240);
    int2*  ovfA    = (int2*)(ws + 524288);
    int2*  ovf2    = (int2*)(ws + 1048576);
    unsigned short* slots16 = (unsigned short*)(ws + 2097152);
    int*   slots32 = (int*)(ws + 2097152);
    __hip_bfloat16* g  = (__hip_bfloat16*)(ws + 11730944);
    __hip_bfloat16* g2 = g;
    unsigned* pairs = (unsigned*)(ws + 24530944);
    __hip_bfloat16* h1 = (__hip_bfloat16*)(ws + 24530944);

    const int GB = (N + 63) / 64;
    const int AB = (E + 2047) / 2048;
    const int EB = (E + 255) / 256;

    if (N <= 65536 && nbuk <= 512) {
        k_detect<<<1, 256, 0, stream>>>((const unsigned*)x, ei, E, flags, gcur, cnt, N, 0);
        k_mega<<<GB + AB, 256, 34816, stream>>>(x, W1, ei, E, N, nbuk, GB,
                                                gcur, pairs, ovfA, ovfAcnt, g, flags);
        k_binB<<<nbuk, 256, 0, stream>>>(gcur, pairs, ovfA, ovfAcnt, cnt, dinv, slots16, ovf2, ovf2cnt, N);
        const int GBL = (N + 31) / 32;
        k_gather1b<<<GBL, 256, 0, stream>>>(g, cnt, dinv, slots16, ovf2, ovf2cnt, b1, h1, flags, N);
        k_gemm<4, 0><<<GB, 256, 0, stream>>>(h1, 0, W2, cnt, g2, flags, N);
        k_gather<64, 0, unsigned short><<<(N + 31) / 32, 256, 0, stream>>>(
            g2, cnt, slots16, ovf2, ovf2cnt, b2, d_out, flags, N);
    } else {
        k_detect<<<64, 256, 0, stream>>>((const unsigned*)x, ei, E, flags, gcur, cnt, N, 1);
        k_build_direct<<<EB, 256, 0, stream>>>(ei, E, N, cnt, slots32, ovf2, ovf2cnt, flags);
        k_gemm<8, 0><<<GB, 256, 0, stream>>>(x, 1, W1, cnt, g, flags, N);
        k_gather<128, 1, int><<<(N + 15) / 16, 256, 0, stream>>>(
            g, cnt, slots32, ovf2, ovf2cnt, b1, h1, flags, N);
        k_gemm<4, 0><<<GB, 256, 0, stream>>>(h1, 0, W2, cnt, g2, flags, N);
        k_gather<64, 0, int><<<(N + 31) / 32, 256, 0, stream>>>(
            g2, cnt, slots32, ovf2, ovf2cnt, b2, d_out, flags, N);
    }
}

// Round 7
// 192.669 us; speedup vs baseline: 1.2074x; 1.2074x over previous
//
#include <hip/hip_runtime.h>
#include <hip/hip_bf16.h>

// GCN 2-layer encoder. R21: R16 build restored exactly (bucketed binA,
// UNSORTED binB — R20's sort cost 41us for zero gather gain). gather1 is now
// SINGLE-PASS over unsplit g [N][128]: each 8-lane group reads both 16B
// halves of a source's 256B row per slot (same bytes + segments as the
// 2-plane scheme, HALF the list-walk/loop/metadata overhead; session data
// R15/R17/R20 proved plane-level L2 temporal locality is worthless).
// Gathers keep packed f32x2 accumulate (v_pk_fma_f32, isolated ~0 cost).
// out[d] = dinv[d] * sum_{s in N(d) U {d}} dinv[s]*h[s] + b,  h = in @ W1

constexpr int FIN = 128;
constexpr int HID = 128;
constexpr int FOUT = 64;
constexpr int CAP = 48;     // adjacency slots per node
constexpr int NPB = 98;     // nodes per bucket
constexpr int BCAP = 3072;  // pairs per bucket region
constexpr int OVF_MAX = 65536;

typedef __attribute__((ext_vector_type(8))) short s16x8;
typedef __attribute__((ext_vector_type(4))) float f32x4;
typedef __attribute__((ext_vector_type(2))) float f32x2;

static __device__ __forceinline__ float bf2f(__hip_bfloat16 v) { return __bfloat162float(v); }
static __device__ __forceinline__ float lo2f(unsigned u) { union { unsigned i; float f; } c; c.i = u << 16; return c.f; }
static __device__ __forceinline__ float hi2f(unsigned u) { union { unsigned i; float f; } c; c.i = u & 0xffff0000u; return c.f; }
static __device__ __forceinline__ unsigned short f2bfu(float f) {
    __hip_bfloat16 h = __float2bfloat16(f);
    union { __hip_bfloat16 h; unsigned short u; } c; c.h = h; return c.u;
}
static __device__ __forceinline__ unsigned pack2(float a, float b) {
    return (unsigned)f2bfu(a) | ((unsigned)f2bfu(b) << 16);
}
// bf16-pair word -> {lo, hi} as f32x2 (same bit ops as lo2f/hi2f)
static __device__ __forceinline__ f32x2 unpk(unsigned u) {
    union { unsigned i; float f; } a, b;
    a.i = u << 16; b.i = u & 0xffff0000u;
    f32x2 r; r[0] = a.f; r[1] = b.f; return r;
}
static __device__ __forceinline__ void acc_add(f32x2* acc, uint4 v) {
    acc[0] += unpk(v.x); acc[1] += unpk(v.y);
    acc[2] += unpk(v.z); acc[3] += unpk(v.w);
}
static __device__ __forceinline__ void acc_fma(f32x2* acc, uint4 v, float w) {
    f32x2 ws; ws[0] = w; ws[1] = w;
    acc[0] += ws * unpk(v.x); acc[1] += ws * unpk(v.y);
    acc[2] += ws * unpk(v.z); acc[3] += ws * unpk(v.w);
}

struct SW { int s; float w; };

// flags detect + zero gcur/ovf counters. zero_cnt!=0 (fallback path): zero cnt.
__global__ __launch_bounds__(256) void k_detect(const unsigned* __restrict__ xw,
                                                const int* __restrict__ eiw,
                                                int E, int* __restrict__ flags,
                                                int* __restrict__ gcur,
                                                int* __restrict__ cnt, int N, int zero_cnt) {
    if (zero_cnt)
        for (long i = (long)blockIdx.x * 256 + threadIdx.x; i < N; i += (long)gridDim.x * 256)
            cnt[i] = 0;
    if (blockIdx.x != 0) return;
    for (int i = threadIdx.x; i < 514; i += 256) gcur[i] = 0;
    __shared__ int s_bf16like, s_oddnz;
    if (threadIdx.x == 0) { s_bf16like = 0; s_oddnz = 0; }
    __syncthreads();
    int c = 0;
    for (int i = threadIdx.x; i < 4096; i += 256) {
        unsigned ex = ((xw[i] & 0xffffu) >> 7) & 0xffu;
        if (ex >= 117u && ex <= 130u) c++;
    }
    atomicAdd(&s_bf16like, c);
    int nz = 0;
    for (int i = threadIdx.x; i < 2048; i += 256)
        if (eiw[2 * i + 1] != 0) nz++;
    atomicAdd(&s_oddnz, nz);
    __syncthreads();
    if (threadIdx.x == 0) {
        flags[0] = (s_bf16like < 2048) ? 1 : 0;
        flags[1] = (s_oddnz == 0) ? 1 : 0;
    }
}

// Mega kernel: blocks [0,GB) = gemm1 (unscaled, UNSPLIT g [N][128]);
//              blocks [GB,GB+AB) = binA edge partition. Dynamic LDS.
__global__ __launch_bounds__(256) void k_mega(const void* __restrict__ Xp,
                                              const void* __restrict__ Wp,
                                              const int* __restrict__ ei, int E, int N,
                                              int nbuk, int GB,
                                              int* __restrict__ gcur,
                                              unsigned* __restrict__ pairs,
                                              int2* __restrict__ ovfA,
                                              int* __restrict__ ovfAcnt,
                                              __hip_bfloat16* __restrict__ G,
                                              const int* __restrict__ flags) {
    extern __shared__ __align__(16) char smem[];
    const int tid = threadIdx.x;
    if ((int)blockIdx.x < GB) {
        // ---------------- GEMM1: g = X @ W1 (unscaled), [N][128] -----------
        short* Wt = (short*)smem;                    // 128x136 bf16 = 34816 B
        const bool f32m = flags[0] != 0;
        for (int i = tid; i < 128 * 128; i += 256) {
            int k = i >> 7, n = i & 127;
            float wv = f32m ? ((const float*)Wp)[(long)k * 128 + n]
                            : bf2f(((const __hip_bfloat16*)Wp)[(long)k * 128 + n]);
            Wt[n * 136 + k] = (short)f2bfu(wv);
        }
        __syncthreads();
        const int w = tid >> 6, lane = tid & 63;
        const int m = lane & 15, quad = lane >> 4;
        const int rowA = blockIdx.x * 64 + w * 16 + m;
        const int rowc = rowA < N ? rowA : N - 1;
        s16x8 afr[4];
#pragma unroll
        for (int kc = 0; kc < 4; ++kc) {
            const int k0 = kc * 32 + quad * 8;
            if (!f32m) {
                afr[kc] = *(const s16x8*)((const __hip_bfloat16*)Xp + (long)rowc * 128 + k0);
            } else {
                const float* p = (const float*)Xp + (long)rowc * 128 + k0;
                s16x8 t;
#pragma unroll
                for (int j = 0; j < 8; ++j) t[j] = (short)f2bfu(p[j]);
                afr[kc] = t;
            }
        }
        const int rbase = blockIdx.x * 64 + w * 16 + quad * 4;
#pragma unroll
        for (int ct = 0; ct < 8; ++ct) {
            f32x4 acc = {0.f, 0.f, 0.f, 0.f};
#pragma unroll
            for (int kc = 0; kc < 4; ++kc) {
                s16x8 bfr = *(const s16x8*)&Wt[(ct * 16 + m) * 136 + kc * 32 + quad * 8];
                acc = __builtin_amdgcn_mfma_f32_16x16x32_bf16(afr[kc], bfr, acc, 0, 0, 0);
            }
            const int cp = ct * 16 + m;
#pragma unroll
            for (int r = 0; r < 4; ++r) {
                int rr = rbase + r;
                if (rr < N)
                    G[(long)rr * 128 + cp] = __float2bfloat16(acc[r]);
            }
        }
    } else {
        // ---------------- binA: edge partition into buckets ----------------
        int* hist = (int*)smem;          // 512 ints
        int* gbase = hist + 512;         // 512 ints
        const long base = (long)(blockIdx.x - GB) * 2048;
        const bool i64 = flags[1] != 0;
        int se[8], de[8];
        for (int b = tid; b < nbuk; b += 256) hist[b] = 0;
        __syncthreads();
#pragma unroll
        for (int j = 0; j < 8; ++j) {
            long i = base + j * 256 + tid;
            int s = 0, d = -1;
            if (i < E) {
                if (i64) { s = ((const int2*)ei)[i].x; d = ((const int2*)(ei + 2 * (long)E))[i].x; }
                else     { s = ei[i]; d = ei[(long)E + i]; }
                if ((unsigned)s >= (unsigned)N || (unsigned)d >= (unsigned)N) d = -1;
            }
            se[j] = s; de[j] = d;
            if (d >= 0) atomicAdd(&hist[d / NPB], 1);
        }
        __syncthreads();
        for (int b = tid; b < nbuk; b += 256) {
            int h = hist[b];
            gbase[b] = h > 0 ? atomicAdd(&gcur[b], h) : 0;
            hist[b] = 0;
        }
        __syncthreads();
#pragma unroll
        for (int j = 0; j < 8; ++j) {
            int d = de[j];
            if (d < 0) continue;
            int b = d / NPB;
            int p = gbase[b] + atomicAdd(&hist[b], 1);
            if (p < BCAP) {
                pairs[(long)b * BCAP + p] = ((unsigned)(d - b * NPB) << 16) | (unsigned)se[j];
            } else {
                int op = atomicAdd(ovfAcnt, 1);
                if (op < OVF_MAX) ovfA[op] = make_int2(d, se[j]);
            }
        }
    }
}

// Phase B: per bucket, build cnt+slots+dinv in LDS (incl. phase-A ovf fold).
__global__ __launch_bounds__(256) void k_binB(const int* __restrict__ gcur,
                                              const unsigned* __restrict__ pairs,
                                              const int2* __restrict__ ovfA,
                                              const int* __restrict__ ovfAcnt,
                                              int* __restrict__ cnt,
                                              float* __restrict__ dinv,
                                              unsigned short* __restrict__ slots,
                                              int2* __restrict__ ovf2,
                                              int* __restrict__ ovf2cnt, int N) {
    __shared__ int cntL[NPB];
    __shared__ __align__(16) unsigned short slotsL[NPB * CAP];
    const int b = blockIdx.x;
    const int tid = threadIdx.x;
    const int d0 = b * NPB;
    const int nd = min(NPB, N - d0);
    if (nd <= 0) return;
    for (int i = tid; i < NPB; i += 256) cntL[i] = 0;
    __syncthreads();
    const int c = min(gcur[b], BCAP);
    const unsigned* pb = pairs + (long)b * BCAP;
    for (int i = tid; i < c; i += 256) {
        unsigned p = pb[i];
        int ld = p >> 16;
        int pos = atomicAdd(&cntL[ld], 1);
        if (pos < CAP) {
            slotsL[ld * CAP + pos] = (unsigned short)(p & 0xffffu);
        } else {
            int op = atomicAdd(ovf2cnt, 1);
            if (op < OVF_MAX) ovf2[op] = make_int2(d0 + ld, (int)(p & 0xffffu));
        }
    }
    int na = *ovfAcnt; na = na < OVF_MAX ? na : OVF_MAX;
    for (int i = tid; i < na; i += 256) {
        int2 p = ovfA[i];
        int ld = p.x - d0;
        if ((unsigned)ld < (unsigned)nd) {
            int pos = atomicAdd(&cntL[ld], 1);
            if (pos < CAP) {
                slotsL[ld * CAP + pos] = (unsigned short)p.y;
            } else {
                int op = atomicAdd(ovf2cnt, 1);
                if (op < OVF_MAX) ovf2[op] = p;
            }
        }
    }
    __syncthreads();
    for (int i = tid; i < nd; i += 256) {
        cnt[d0 + i] = cntL[i];
        dinv[d0 + i] = rsqrtf((float)(cntL[i] + 1));
    }
    const uint4* sv = (const uint4*)slotsL;
    uint4* gv = (uint4*)(slots + (long)d0 * CAP);
    const int total8 = (nd * CAP) >> 3;
    for (int i = tid; i < total8; i += 256) gv[i] = sv[i];
}

// Fallback direct build for N > 65536 (int slots). cnt must be pre-zeroed.
__global__ __launch_bounds__(256) void k_build_direct(const int* __restrict__ ei, int E, int N,
                                                      int* __restrict__ cnt,
                                                      int* __restrict__ slots,
                                                      int2* __restrict__ ovf2,
                                                      int* __restrict__ ovf2cnt,
                                                      const int* __restrict__ flags) {
    long i = (long)blockIdx.x * 256 + threadIdx.x;
    if (i >= E) return;
    int s, d;
    if (flags[1]) { s = ((const int2*)ei)[i].x; d = ((const int2*)(ei + 2 * (long)E))[i].x; }
    else          { s = ei[i]; d = ei[(long)E + i]; }
    if ((unsigned)s >= (unsigned)N || (unsigned)d >= (unsigned)N) return;
    int pos = atomicAdd(&cnt[d], 1);
    if (pos < CAP) {
        slots[(long)d * CAP + pos] = s;
    } else {
        int op = atomicAdd(ovf2cnt, 1);
        if (op < OVF_MAX) ovf2[op] = make_int2(d, s);
    }
}

// Scaled MFMA GEMM (runs after binB): G = bf16( rsqrt(cnt+1) * (X @ W) ).
template<int CT, int SPLIT>
__global__ __launch_bounds__(256) void k_gemm(const void* __restrict__ Xp, int x_follows_flag,
                                              const void* __restrict__ Wp,
                                              const int* __restrict__ cnt,
                                              __hip_bfloat16* __restrict__ G,
                                              const int* __restrict__ flags, int N) {
    constexpr int C = CT * 16;
    __shared__ __align__(16) short Wt[C * 136];
    const bool f32m = flags[0] != 0;
    const bool xf32 = (x_follows_flag != 0) && f32m;
    const int tid = threadIdx.x;
    for (int i = tid; i < 128 * C; i += 256) {
        int k = i / C, n = i % C;
        float wv = f32m ? ((const float*)Wp)[(long)k * C + n]
                        : bf2f(((const __hip_bfloat16*)Wp)[(long)k * C + n]);
        Wt[n * 136 + k] = (short)f2bfu(wv);
    }
    __syncthreads();
    const int w = tid >> 6, lane = tid & 63;
    const int m = lane & 15, quad = lane >> 4;
    const int rowA = blockIdx.x * 64 + w * 16 + m;
    const int rowc = rowA < N ? rowA : N - 1;
    s16x8 afr[4];
#pragma unroll
    for (int kc = 0; kc < 4; ++kc) {
        const int k0 = kc * 32 + quad * 8;
        if (!xf32) {
            afr[kc] = *(const s16x8*)((const __hip_bfloat16*)Xp + (long)rowc * 128 + k0);
        } else {
            const float* p = (const float*)Xp + (long)rowc * 128 + k0;
            s16x8 t;
#pragma unroll
            for (int j = 0; j < 8; ++j) t[j] = (short)f2bfu(p[j]);
            afr[kc] = t;
        }
    }
    const int rbase = blockIdx.x * 64 + w * 16 + quad * 4;
    float dv[4];
#pragma unroll
    for (int r = 0; r < 4; ++r) {
        int rr = min(rbase + r, N - 1);
        dv[r] = rsqrtf((float)(cnt[rr] + 1));
    }
#pragma unroll
    for (int ct = 0; ct < CT; ++ct) {
        f32x4 acc = {0.f, 0.f, 0.f, 0.f};
#pragma unroll
        for (int kc = 0; kc < 4; ++kc) {
            s16x8 bfr = *(const s16x8*)&Wt[(ct * 16 + m) * 136 + kc * 32 + quad * 8];
            acc = __builtin_amdgcn_mfma_f32_16x16x32_bf16(afr[kc], bfr, acc, 0, 0, 0);
        }
#pragma unroll
        for (int r = 0; r < 4; ++r) {
            int rr = rbase + r;
            if (rr < N) {
                long off;
                if (SPLIT) {
                    const int plane = ct / (CT / 2);
                    const int cp = (ct % (CT / 2)) * 16 + m;
                    off = (long)plane * N * (C / 2) + (long)rr * (C / 2) + cp;
                } else {
                    off = (long)rr * C + ct * 16 + m;
                }
                G[off] = __float2bfloat16(dv[r] * acc[r]);
            }
        }
    }
}

// R21 gather, layer 1: SINGLE PASS over unsplit g [N][128]. Block owns 32
// nodes; slots + per-source dinv staged to LDS once (stride-49 pad). Each
// 8-lane group reads 2x uint4 per slot (both halves of the 256B source row).
// g UNscaled; dinv[s] applied per source. Packed f32x2 accumulate.
__global__ __launch_bounds__(256) void k_gather1c(const __hip_bfloat16* __restrict__ G,
                                                  const int* __restrict__ cnt,
                                                  const float* __restrict__ dinv,
                                                  const unsigned short* __restrict__ slots,
                                                  const int2* __restrict__ ovf2,
                                                  const int* __restrict__ ovf2cnt,
                                                  const void* __restrict__ b1,
                                                  __hip_bfloat16* __restrict__ h1,
                                                  const int* __restrict__ flags, int N) {
    __shared__ int cntL[32];
    __shared__ float wsL[32];
    __shared__ __align__(16) SW swL[32 * 49];     // 12544 B, pad 48->49
    const int tid = threadIdx.x;
    const int n0 = blockIdx.x * 32;
    const int nd = min(32, N - n0);
    for (int i = tid; i < nd; i += 256) {
        cntL[i] = cnt[n0 + i];
        wsL[i] = dinv[n0 + i];
    }
    __syncthreads();
    for (int j = tid; j < 32 * CAP; j += 256) {
        const int ni = j / CAP, sl = j - ni * CAP;
        if (ni < nd) {
            const int mm = min(cntL[ni], CAP);
            if (sl < mm) {
                const int s = slots[(long)(n0 + ni) * CAP + sl];
                swL[ni * 49 + sl].s = s;
                swL[ni * 49 + sl].w = dinv[s];
            }
        }
    }
    __syncthreads();
    const int grp = tid >> 3, lane = tid & 7;
    if (grp >= nd) return;                        // all barriers done
    const int node = n0 + grp;
    const int cd = cntL[grp];
    const int m = cd < CAP ? cd : CAP;
    const float wself = wsL[grp];
    const SW* sw = &swL[grp * 49];
    const bool f32m = flags[0] != 0;
    f32x2 accA[4] = {};                           // cols lane*8 .. lane*8+7
    f32x2 accB[4] = {};                           // cols 64+lane*8 ..
    float* aA = (float*)accA;
    float* aB = (float*)accB;
    {
        const uint4* sp = (const uint4*)(G + (long)node * 128);
        acc_fma(accA, sp[lane], wself);           // self loop, both halves
        acc_fma(accB, sp[8 + lane], wself);
    }
    int i = 0;
    for (; i + 3 < m; i += 4) {
        SW a0 = sw[i], a1 = sw[i + 1], a2 = sw[i + 2], a3 = sw[i + 3];
        const uint4* p0 = (const uint4*)(G + (long)a0.s * 128);
        const uint4* p1 = (const uint4*)(G + (long)a1.s * 128);
        const uint4* p2 = (const uint4*)(G + (long)a2.s * 128);
        const uint4* p3 = (const uint4*)(G + (long)a3.s * 128);
        uint4 v0a = p0[lane], v0b = p0[8 + lane];
        uint4 v1a = p1[lane], v1b = p1[8 + lane];
        uint4 v2a = p2[lane], v2b = p2[8 + lane];
        uint4 v3a = p3[lane], v3b = p3[8 + lane];
        acc_fma(accA, v0a, a0.w); acc_fma(accB, v0b, a0.w);
        acc_fma(accA, v1a, a1.w); acc_fma(accB, v1b, a1.w);
        acc_fma(accA, v2a, a2.w); acc_fma(accB, v2b, a2.w);
        acc_fma(accA, v3a, a3.w); acc_fma(accB, v3b, a3.w);
    }
    for (; i < m; ++i) {
        SW a = sw[i];
        const uint4* p = (const uint4*)(G + (long)a.s * 128);
        acc_fma(accA, p[lane], a.w);
        acc_fma(accB, p[8 + lane], a.w);
    }
    if (cd > CAP) {
        int oc = *ovf2cnt; oc = oc < OVF_MAX ? oc : OVF_MAX;
        for (int j = 0; j < oc; ++j)
            if (ovf2[j].x == node) {
                int s0 = ovf2[j].y;
                float w0 = dinv[s0];
                const uint4* p = (const uint4*)(G + (long)s0 * 128);
                acc_fma(accA, p[lane], w0);
                acc_fma(accB, p[8 + lane], w0);
            }
    }
    float bvA[8], bvB[8];
    if (f32m) {
        const float4* bpA = (const float4*)((const float*)b1 + lane * 8);
        const float4* bpB = (const float4*)((const float*)b1 + 64 + lane * 8);
        float4 a0 = bpA[0], a1 = bpA[1], b0 = bpB[0], b1v = bpB[1];
        bvA[0] = a0.x; bvA[1] = a0.y; bvA[2] = a0.z; bvA[3] = a0.w;
        bvA[4] = a1.x; bvA[5] = a1.y; bvA[6] = a1.z; bvA[7] = a1.w;
        bvB[0] = b0.x; bvB[1] = b0.y; bvB[2] = b0.z; bvB[3] = b0.w;
        bvB[4] = b1v.x; bvB[5] = b1v.y; bvB[6] = b1v.z; bvB[7] = b1v.w;
    } else {
        uint4 ba = *(const uint4*)((const __hip_bfloat16*)b1 + lane * 8);
        uint4 bb = *(const uint4*)((const __hip_bfloat16*)b1 + 64 + lane * 8);
        bvA[0] = lo2f(ba.x); bvA[1] = hi2f(ba.x); bvA[2] = lo2f(ba.y); bvA[3] = hi2f(ba.y);
        bvA[4] = lo2f(ba.z); bvA[5] = hi2f(ba.z); bvA[6] = lo2f(ba.w); bvA[7] = hi2f(ba.w);
        bvB[0] = lo2f(bb.x); bvB[1] = hi2f(bb.x); bvB[2] = lo2f(bb.y); bvB[3] = hi2f(bb.y);
        bvB[4] = lo2f(bb.z); bvB[5] = hi2f(bb.z); bvB[6] = lo2f(bb.w); bvB[7] = hi2f(bb.w);
    }
    float oA[8], oB[8];
#pragma unroll
    for (int c = 0; c < 8; ++c) {
        float vA = wself * aA[c] + bvA[c];
        float vB = wself * aB[c] + bvB[c];
        oA[c] = vA > 0.f ? vA : 0.f;
        oB[c] = vB > 0.f ? vB : 0.f;
    }
    uint4 pA = { pack2(oA[0], oA[1]), pack2(oA[2], oA[3]), pack2(oA[4], oA[5]), pack2(oA[6], oA[7]) };
    uint4 pB = { pack2(oB[0], oB[1]), pack2(oB[2], oB[3]), pack2(oB[4], oB[5]), pack2(oB[6], oB[7]) };
    uint4* hp = (uint4*)(h1 + (long)node * 128);
    hp[lane] = pA;
    hp[8 + lane] = pB;
}

// Full-row gather over pre-scaled G (layer 2 and fallback layer 1).
template<int F, int LAYER1, typename ST>
__global__ __launch_bounds__(256) void k_gather(const __hip_bfloat16* __restrict__ G,
                                                const int* __restrict__ cnt,
                                                const ST* __restrict__ slots,
                                                const int2* __restrict__ ovf2,
                                                const int* __restrict__ ovf2cnt,
                                                const void* __restrict__ bias,
                                                void* __restrict__ outp,
                                                const int* __restrict__ flags, int N) {
    constexpr int L = F / 8;
    constexpr int NODES = 256 / L;
    const int tid = threadIdx.x;
    const int grp = tid / L, lane = tid % L;
    const int node = blockIdx.x * NODES + grp;
    if (node >= N) return;
    const int cd = cnt[node];
    const float wself = rsqrtf((float)(cd + 1));
    const int m = cd < CAP ? cd : CAP;
    const ST* sl = slots + (long)node * CAP;
    f32x2 acc2[4] = {};
    float* acc = (float*)acc2;
    acc_add(acc2, ((const uint4*)(G + (long)node * F))[lane]);
    int i = 0;
    for (; i + 7 < m; i += 8) {
        int s0 = sl[i], s1 = sl[i + 1], s2 = sl[i + 2], s3 = sl[i + 3];
        int s4 = sl[i + 4], s5 = sl[i + 5], s6 = sl[i + 6], s7 = sl[i + 7];
        uint4 v0 = ((const uint4*)(G + (long)s0 * F))[lane];
        uint4 v1 = ((const uint4*)(G + (long)s1 * F))[lane];
        uint4 v2 = ((const uint4*)(G + (long)s2 * F))[lane];
        uint4 v3 = ((const uint4*)(G + (long)s3 * F))[lane];
        uint4 v4 = ((const uint4*)(G + (long)s4 * F))[lane];
        uint4 v5 = ((const uint4*)(G + (long)s5 * F))[lane];
        uint4 v6 = ((const uint4*)(G + (long)s6 * F))[lane];
        uint4 v7 = ((const uint4*)(G + (long)s7 * F))[lane];
        acc_add(acc2, v0); acc_add(acc2, v1); acc_add(acc2, v2); acc_add(acc2, v3);
        acc_add(acc2, v4); acc_add(acc2, v5); acc_add(acc2, v6); acc_add(acc2, v7);
    }
    for (; i + 3 < m; i += 4) {
        int s0 = sl[i], s1 = sl[i + 1], s2 = sl[i + 2], s3 = sl[i + 3];
        uint4 v0 = ((const uint4*)(G + (long)s0 * F))[lane];
        uint4 v1 = ((const uint4*)(G + (long)s1 * F))[lane];
        uint4 v2 = ((const uint4*)(G + (long)s2 * F))[lane];
        uint4 v3 = ((const uint4*)(G + (long)s3 * F))[lane];
        acc_add(acc2, v0); acc_add(acc2, v1); acc_add(acc2, v2); acc_add(acc2, v3);
    }
    for (; i < m; ++i)
        acc_add(acc2, ((const uint4*)(G + (long)sl[i] * F))[lane]);
    if (cd > CAP) {
        int oc = *ovf2cnt; oc = oc < OVF_MAX ? oc : OVF_MAX;
        for (int j = 0; j < oc; ++j)
            if (ovf2[j].x == node)
                acc_add(acc2, ((const uint4*)(G + (long)ovf2[j].y * F))[lane]);
    }
    const bool f32m = flags[0] != 0;
    const int c0 = lane * 8;
    float bv[8];
    if (f32m) {
        const float4* bp = (const float4*)((const float*)bias + c0);
        float4 b0 = bp[0], b1 = bp[1];
        bv[0] = b0.x; bv[1] = b0.y; bv[2] = b0.z; bv[3] = b0.w;
        bv[4] = b1.x; bv[5] = b1.y; bv[6] = b1.z; bv[7] = b1.w;
    } else {
        uint4 b = *(const uint4*)((const __hip_bfloat16*)bias + c0);
        bv[0] = lo2f(b.x); bv[1] = hi2f(b.x); bv[2] = lo2f(b.y); bv[3] = hi2f(b.y);
        bv[4] = lo2f(b.z); bv[5] = hi2f(b.z); bv[6] = lo2f(b.w); bv[7] = hi2f(b.w);
    }
    float o[8];
#pragma unroll
    for (int c = 0; c < 8; ++c) {
        float v = wself * acc[c] + bv[c];
        o[c] = (LAYER1 && v < 0.f) ? 0.f : v;
    }
    if (LAYER1 || !f32m) {
        uint4 pv = { pack2(o[0], o[1]), pack2(o[2], o[3]), pack2(o[4], o[5]), pack2(o[6], o[7]) };
        ((uint4*)outp)[(long)node * L + lane] = pv;
    } else {
        float4* op = (float4*)((float*)outp + (long)node * F + c0);
        op[0] = make_float4(o[0], o[1], o[2], o[3]);
        op[1] = make_float4(o[4], o[5], o[6], o[7]);
    }
}

extern "C" void kernel_launch(void* const* d_in, const int* in_sizes, int n_in,
                              void* d_out, int out_size, void* d_ws, size_t ws_size,
                              hipStream_t stream) {
    const void* x  = d_in[0];
    const int*  ei = (const int*)d_in[1];
    const void* W1 = d_in[2];
    const void* b1 = d_in[3];
    const void* W2 = d_in[4];
    const void* b2 = d_in[5];

    const int N = in_sizes[0] / FIN;   // 50000
    const int E = in_sizes[1] / 2;     // 800000
    const int nbuk = (N + NPB - 1) / NPB;   // 511 (<=512 for u16 path)

    // ws layout (bytes), peak ~37.3MB:
    //   flags @0; gcur @4096 (512+2 ints)
    //   cnt @65536 (4N); dinv @266240 (4N)
    //   ovfA @524288; ovf2 @1048576
    //   slots @2097152 (u16 4.8MB / int 9.6MB)
    //   g @11730944 (12.8MB, [N][128]; g2 overlays)
    //   pairs @24530944 (6.28MB; h1 overlays after binB)
    char* ws = (char*)d_ws;
    int*   flags   = (int*)ws;
    int*   gcur    = (int*)(ws + 4096);
    int*   ovfAcnt = gcur + 512;
    int*   ovf2cnt = gcur + 513;
    int*   cnt     = (int*)(ws + 65536);
    float* dinv    = (float*)(ws + 266240);
    int2*  ovfA    = (int2*)(ws + 524288);
    int2*  ovf2    = (int2*)(ws + 1048576);
    unsigned short* slots16 = (unsigned short*)(ws + 2097152);
    int*   slots32 = (int*)(ws + 2097152);
    __hip_bfloat16* g  = (__hip_bfloat16*)(ws + 11730944);
    __hip_bfloat16* g2 = g;
    unsigned* pairs = (unsigned*)(ws + 24530944);
    __hip_bfloat16* h1 = (__hip_bfloat16*)(ws + 24530944);

    const int GB = (N + 63) / 64;
    const int AB = (E + 2047) / 2048;
    const int EB = (E + 255) / 256;

    if (N <= 65536 && nbuk <= 512) {
        k_detect<<<1, 256, 0, stream>>>((const unsigned*)x, ei, E, flags, gcur, cnt, N, 0);
        k_mega<<<GB + AB, 256, 34816, stream>>>(x, W1, ei, E, N, nbuk, GB,
                                                gcur, pairs, ovfA, ovfAcnt, g, flags);
        k_binB<<<nbuk, 256, 0, stream>>>(gcur, pairs, ovfA, ovfAcnt, cnt, dinv, slots16, ovf2, ovf2cnt, N);
        const int GBL = (N + 31) / 32;
        k_gather1c<<<GBL, 256, 0, stream>>>(g, cnt, dinv, slots16, ovf2, ovf2cnt, b1, h1, flags, N);
        k_gemm<4, 0><<<GB, 256, 0, stream>>>(h1, 0, W2, cnt, g2, flags, N);
        k_gather<64, 0, unsigned short><<<(N + 31) / 32, 256, 0, stream>>>(
            g2, cnt, slots16, ovf2, ovf2cnt, b2, d_out, flags, N);
    } else {
        k_detect<<<64, 256, 0, stream>>>((const unsigned*)x, ei, E, flags, gcur, cnt, N, 1);
        k_build_direct<<<EB, 256, 0, stream>>>(ei, E, N, cnt, slots32, ovf2, ovf2cnt, flags);
        k_gemm<8, 0><<<GB, 256, 0, stream>>>(x, 1, W1, cnt, g, flags, N);
        k_gather<128, 1, int><<<(N + 15) / 16, 256, 0, stream>>>(
            g, cnt, slots32, ovf2, ovf2cnt, b1, h1, flags, N);
        k_gemm<4, 0><<<GB, 256, 0, stream>>>(h1, 0, W2, cnt, g2, flags, N);
        k_gather<64, 0, int><<<(N + 31) / 32, 256, 0, stream>>>(
            g2, cnt, slots32, ovf2, ovf2cnt, b2, d_out, flags, N);
    }
}